// Round 8
// baseline (148.892 us; speedup 1.0000x reference)
//
#include <hip/hip_runtime.h>

typedef unsigned long long u64;
typedef unsigned u32;

#define BATCH 16
#define Hh 512
#define Ww 512
#define IMG (Hh * Ww)          // 262144
#define TOT (BATCH * IMG)      // 4194304
#define WPI (IMG / 64)         // 4096 words per image
#define WROW 8                 // words per row
#define NWORDS (TOT / 64)      // 65536
#define MIN_SIZE 262           // keep strictly greater
#define GHASH 32768            // global root->size hash (power of 2)
#define RCAP 65536             // root list capacity

#define BAND 16
#define HALO 4
#define BROWS (BAND + 2 * HALO)     // 24
#define BWORDS (BROWS * WROW)       // 192
#define NODES (BAND * Ww)           // 8192 nodes per band

// run start within a 64-bit word: nearest zero at-or-below bit s, +1.
__device__ __forceinline__ u32 runstart(u64 bits, int s) {
    u64 ms = (s >= 63) ? ~0ULL : ((1ULL << (s + 1)) - 1);
    u64 nz = ~bits & ms;
    return nz ? (u32)(64 - __clzll(nz)) : 0u;
}
// run length starting at set bit s (within word)
__device__ __forceinline__ u32 runlen(u64 bits, int s) {
    u64 v = ~(bits >> s);
    return v ? (u32)(__ffsll(v) - 1) : (u32)(64 - s);
}

__device__ __forceinline__ u64 morph_word(const u64* M, int w, int rr, bool er) {
    const u64 B = er ? ~0ULL : 0ULL;
    int wx = w & 7;
    u64 cc = M[w];
    u64 lf = (cc << 1) | (wx > 0 ? (M[w - 1] >> 63) : (er ? 1ULL : 0ULL));
    u64 rt = (cc >> 1) | (wx < 7 ? (M[w + 1] << 63) : (er ? (1ULL << 63) : 0ULL));
    u64 up = (rr <= 0)      ? B : (w >= WROW          ? M[w - WROW] : B);
    u64 dn = (rr >= Hh - 1) ? B : (w < BWORDS - WROW  ? M[w + WROW] : B);
    return er ? (cc & lf & rt & up & dn) : (cc | lf | rt | up | dn);
}

// ---------------- union-find primitives (LDS or global) ----------------
template <typename P>
__device__ __forceinline__ u32 uf_find_halve(P L, u32 x) {
    while (true) {
        u32 p = L[x];
        if (p == x) return x;
        u32 gp = L[p];
        if (gp == p) return p;
        atomicMin(&L[x], gp);   // halving: gp <= p < x, monotone-safe
        x = gp;
    }
}
template <typename P>
__device__ __forceinline__ void uf_merge(P L, u32 a, u32 b) {
    while (true) {
        a = uf_find_halve(L, a);
        b = uf_find_halve(L, b);
        if (a == b) return;
        if (a > b) { u32 t = a; a = b; b = t; }   // a < b
        u32 old = atomicMin(&L[b], a);
        if (old == b) return;
        b = old;
    }
}

// ========== fused vote + morph + band CCL ==========
// 16 img x 32 bands = 512 blocks x 256 thr. Band = 16 owned rows (+4 halo).
// Also zeroes the global hash. Appends (band-root, size) to compact list.
__global__ __launch_bounds__(256) void vmc_kernel(const float* __restrict__ x,
                                                  u64* __restrict__ mp,
                                                  u32* __restrict__ L,
                                                  u32* __restrict__ hkeys,
                                                  u32* __restrict__ hvals,
                                                  u32* __restrict__ rootlist,
                                                  u32* __restrict__ sizelist,
                                                  u32* __restrict__ rcount) {
    __shared__ u64 M[BWORDS];          // 1.5 KB
    __shared__ u32 Ll[NODES];          // 32 KB
    __shared__ u32 sz[NODES / 2];      // 16 KB, packed u16 pairs
    int blk = blockIdx.x;
    int img = blk >> 5;
    int r0  = (blk & 31) * BAND;
    int t = threadIdx.x, lane = t & 63, wv = t >> 6;

    // zero global hash: 512*256 = 131072 threads >= 2*GHASH = 65536
    { int idx = blk * 256 + t;
      if (idx < GHASH) hkeys[idx] = 0u;
      else if (idx < 2 * GHASH) hvals[idx - GHASH] = 0u; }

    // ---- vote + load (wave64 ballot -> one word) ----
    const float* xb = x + (size_t)img * 4 * IMG;
    for (int w = wv; w < BWORDS; w += 4) {
        int rr = r0 - HALO + (w >> 3);
        u64 bits = 0;
        if (rr >= 0 && rr < Hh) {                  // wave-uniform
            size_t p = (size_t)rr * Ww + (size_t)(w & 7) * 64 + lane;
            bool p1 = xb[p + (size_t)IMG]     > 0.5f;
            bool p2 = xb[p + 2 * (size_t)IMG] > 0.5f;
            bool p3 = xb[p + 3 * (size_t)IMG] > 0.5f;
            bits = __ballot(p1 | (p2 & p3));
        }
        if (lane == 0) M[w] = bits;
    }
    __syncthreads();

    // ---- 4 morph passes (close: D,E; open: E,D) ----
    #pragma unroll
    for (int pass = 0; pass < 4; ++pass) {
        const bool er = (pass == 1 || pass == 2);
        u64 res = 0;
        if (t < BWORDS) res = morph_word(M, t, r0 - HALO + (t >> 3), er);
        __syncthreads();
        if (t < BWORDS) M[t] = res;
        __syncthreads();
    }
    // owned band words: M[32 .. 159] (row r -> M[32 + r*8 + w])
    if (t < BAND * WROW)
        mp[(size_t)img * WPI + (size_t)r0 * WROW + t] = M[HALO * WROW + t];

    // ---- band CCL: nodes = within-word run starts ----
    for (int i = t; i < NODES; i += 256) Ll[i] = (u32)i;
    for (int i = t; i < NODES / 2; i += 256) sz[i] = 0u;
    __syncthreads();

    // unions: 120 vertical tasks (15 row-pairs x 8 words) + 112 horizontal
    if (t < 120) {
        int rp = t >> 3, w = t & 7;                  // rows (rp, rp+1)
        u64 a = M[32 + rp * 8 + w], b = M[32 + (rp + 1) * 8 + w];
        u64 ov = a & b, seg = ov & ~(ov << 1);
        while (seg) {
            int s = __ffsll(seg) - 1; seg &= seg - 1;
            uf_merge((u32*)Ll, (u32)(rp * Ww + w * 64) + runstart(a, s),
                               (u32)((rp + 1) * Ww + w * 64) + runstart(b, s));
        }
    } else if (t < 232) {
        int ht = t - 120, r = ht / 7, w = 1 + ht % 7;  // word pair (w-1, w)
        u64 a = M[32 + r * 8 + w - 1], b = M[32 + r * 8 + w];
        if ((a >> 63) & b & 1ULL)
            uf_merge((u32*)Ll, (u32)(r * Ww + (w - 1) * 64) + runstart(a, 63),
                               (u32)(r * Ww + w * 64));
    }
    __syncthreads();

    // flatten per run + write global L + accumulate sizes (128 word tasks)
    u32 pbase = (u32)img * IMG + (u32)r0 * Ww;    // node n -> pixel pbase+n
    if (t < 128) {
        u64 bits = M[32 + t];
        u32 nb = (u32)(t >> 3) * Ww + (u32)(t & 7) * 64;
        u64 st = bits & ~(bits << 1);
        while (st) {
            int s = __ffsll(st) - 1; st &= st - 1;
            u32 n = nb + (u32)s;
            u32 r = n, p = Ll[r];
            while (p != r) { r = p; p = Ll[r]; }   // read-only chase
            Ll[n] = r;                              // compress (own word's nodes)
            L[pbase + n] = pbase + r;
            atomicAdd(&sz[r >> 1], runlen(bits, s) << ((r & 1) * 16));
        }
    }
    __syncthreads();

    // append band roots to compact list
    if (t < 128) {
        u64 bits = M[32 + t];
        u32 nb = (u32)(t >> 3) * Ww + (u32)(t & 7) * 64;
        u64 st = bits & ~(bits << 1);
        while (st) {
            int s = __ffsll(st) - 1; st &= st - 1;
            u32 n = nb + (u32)s;
            if (Ll[n] == n) {
                u32 size = (sz[n >> 1] >> ((n & 1) * 16)) & 0xFFFFu;
                u32 idx = atomicAdd(rcount, 1u);
                if (idx < RCAP) { rootlist[idx] = pbase + n; sizelist[idx] = size; }
            }
        }
    }
}

// ========== cross-band boundary merges ==========
#define BITEMS (BATCH * 31 * WROW)    // 3968
__global__ void border_merge_kernel(const u64* __restrict__ mp, u32* L) {
    int e = blockIdx.x * blockDim.x + threadIdx.x;
    if (e >= BITEMS) return;
    int w = e & 7, k = (e >> 3) % 31 + 1, img = e / (31 * 8);
    int R = k * BAND;                  // boundary rows R-1, R
    const u64* ib = mp + (size_t)img * WPI;
    u64 a = ib[(size_t)(R - 1) * WROW + w];
    u64 b = ib[(size_t)R * WROW + w];
    u64 ov = a & b, seg = ov & ~(ov << 1);
    u32 ga = (u32)img * IMG + (u32)(R - 1) * Ww + (u32)(w * 64);
    while (seg) {
        int s = __ffsll(seg) - 1; seg &= seg - 1;
        uf_merge(L, ga + runstart(a, s), ga + (u32)Ww + runstart(b, s));
    }
}

// ========== accumulate band-root sizes into global hash ==========
__global__ __launch_bounds__(256) void accum_kernel(u32* __restrict__ L,
                                                    const u32* __restrict__ rootlist,
                                                    const u32* __restrict__ sizelist,
                                                    const u32* __restrict__ rcount,
                                                    u32* __restrict__ hkeys,
                                                    u32* __restrict__ hvals) {
    u32 n = *rcount; if (n > RCAP) n = RCAP;
    u32 idx = blockIdx.x * 256 + threadIdx.x;
    if (idx >= n) return;
    u32 gi = rootlist[idx], size = sizelist[idx];
    u32 r = gi, p = L[r];
    while (p != r) { r = p; p = L[r]; }    // read-only chase
    L[gi] = r;                              // compress (unique gi per entry)
    u32 h = (r * 2654435761u) & (GHASH - 1);
    while (true) {
        u32 k = atomicCAS(&hkeys[h], 0u, r + 1u);
        if (k == 0u || k == r + 1u) { atomicAdd(&hvals[h], size); break; }
        h = (h + 1) & (GHASH - 1);
    }
}

// ========== final: keep-mask per word, coalesced float4 writes ==========
__global__ __launch_bounds__(256) void final_kernel(const u64* __restrict__ mp,
                                                    const u32* __restrict__ L,
                                                    const u32* __restrict__ hkeys,
                                                    const u32* __restrict__ hvals,
                                                    float* __restrict__ out) {
    __shared__ u64 km[256];
    int tid = threadIdx.x;
    int widx = blockIdx.x * 256 + tid;
    u64 bits = mp[widx];
    u32 gbase = (u32)widx * 64;
    u64 keep = 0;
    u64 st = bits & ~(bits << 1);
    while (st) {
        int s = __ffsll(st) - 1; st &= st - 1;
        u32 r = L[gbase + (u32)s];           // band root
        u32 p = L[r];
        while (p != r) { r = p; p = L[r]; }  // short chase to final root
        u32 h = (r * 2654435761u) & (GHASH - 1);
        u32 szv = 0;
        while (true) {
            u32 k = hkeys[h];
            if (k == r + 1u) { szv = hvals[h]; break; }
            if (k == 0u) break;
            h = (h + 1) & (GHASH - 1);
        }
        if (szv > MIN_SIZE) {
            u32 len = runlen(bits, s);
            keep |= (len == 64 ? ~0ULL : ((1ULL << len) - 1ULL)) << s;
        }
    }
    km[tid] = keep;
    __syncthreads();
    float4* o4 = (float4*)out + (size_t)blockIdx.x * 4096;
    for (int i = tid; i < 4096; i += 256) {
        u32 nib = (u32)(km[i >> 4] >> ((i & 15) * 4)) & 0xFu;
        o4[i] = make_float4(nib & 1u ? 1.f : 0.f, nib & 2u ? 1.f : 0.f,
                            nib & 4u ? 1.f : 0.f, nib & 8u ? 1.f : 0.f);
    }
}

extern "C" void kernel_launch(void* const* d_in, const int* in_sizes, int n_in,
                              void* d_out, int out_size, void* d_ws, size_t ws_size,
                              hipStream_t stream) {
    const float* x = (const float*)d_in[0];
    float* out = (float*)d_out;

    // ws: mp 512KB | L 16MB | hkeys 128KB | hvals 128KB | rootlist 256KB |
    //     sizelist 256KB | rcount 4B        (total ~17.3MB; 24MB was OK in R1)
    u64* mp = (u64*)d_ws;
    u32* L  = (u32*)(mp + NWORDS);
    u32* hkeys = L + TOT;
    u32* hvals = hkeys + GHASH;
    u32* rootlist = hvals + GHASH;
    u32* sizelist = rootlist + RCAP;
    u32* rcount   = sizelist + RCAP;

    const int block = 256;

    hipMemsetAsync(rcount, 0, sizeof(u32), stream);
    vmc_kernel<<<BATCH * 32, block, 0, stream>>>(x, mp, L, hkeys, hvals,
                                                 rootlist, sizelist, rcount);
    border_merge_kernel<<<(BITEMS + block - 1) / block, block, 0, stream>>>(mp, L);
    accum_kernel<<<RCAP / block, block, 0, stream>>>(L, rootlist, sizelist, rcount,
                                                     hkeys, hvals);
    final_kernel<<<NWORDS / block, block, 0, stream>>>(mp, L, hkeys, hvals, out);
}

// Round 9
// 108.944 us; speedup vs baseline: 1.3667x; 1.3667x over previous
//
#include <hip/hip_runtime.h>

typedef unsigned long long u64;
typedef unsigned u32;

#define BATCH 16
#define Hh 512
#define Ww 512
#define IMG (Hh * Ww)          // 262144
#define TOT (BATCH * IMG)      // 4194304
#define WPI (IMG / 64)         // 4096 words per image
#define WROW 8                 // words per row
#define NWORDS (TOT / 64)      // 65536
#define MIN_SIZE 262           // keep strictly greater
#define GHASH 131072           // global root->size hash (power of 2, load ~0.3)
#define LHASH 2048             // per-block hash in count

#define BAND 16
#define HALO 4
#define BROWS (BAND + 2 * HALO)     // 24
#define BWORDS (BROWS * WROW)       // 192
#define NODES (BAND * Ww)           // 8192 nodes per band

// run start within a 64-bit word: nearest zero at-or-below bit s, +1.
__device__ __forceinline__ u32 runstart(u64 bits, int s) {
    u64 ms = (s >= 63) ? ~0ULL : ((1ULL << (s + 1)) - 1);
    u64 nz = ~bits & ms;
    return nz ? (u32)(64 - __clzll(nz)) : 0u;
}
// run length starting at set bit s (within word)
__device__ __forceinline__ u32 runlen(u64 bits, int s) {
    u64 v = ~(bits >> s);
    return v ? (u32)(__ffsll(v) - 1) : (u32)(64 - s);
}

__device__ __forceinline__ u64 morph_word(const u64* M, int w, int rr, bool er) {
    const u64 B = er ? ~0ULL : 0ULL;
    int wx = w & 7;
    u64 cc = M[w];
    u64 lf = (cc << 1) | (wx > 0 ? (M[w - 1] >> 63) : (er ? 1ULL : 0ULL));
    u64 rt = (cc >> 1) | (wx < 7 ? (M[w + 1] << 63) : (er ? (1ULL << 63) : 0ULL));
    u64 up = (rr <= 0)      ? B : (w >= WROW          ? M[w - WROW] : B);
    u64 dn = (rr >= Hh - 1) ? B : (w < BWORDS - WROW  ? M[w + WROW] : B);
    return er ? (cc & lf & rt & up & dn) : (cc | lf | rt | up | dn);
}

// ---------------- union-find primitives (LDS or global) ----------------
template <typename P>
__device__ __forceinline__ u32 uf_find_halve(P L, u32 x) {
    while (true) {
        u32 p = L[x];
        if (p == x) return x;
        u32 gp = L[p];
        if (gp == p) return p;
        atomicMin(&L[x], gp);   // halving: gp <= p < x, monotone-safe
        x = gp;
    }
}
template <typename P>
__device__ __forceinline__ void uf_merge(P L, u32 a, u32 b) {
    while (true) {
        a = uf_find_halve(L, a);
        b = uf_find_halve(L, b);
        if (a == b) return;
        if (a > b) { u32 t = a; a = b; b = t; }   // a < b
        u32 old = atomicMin(&L[b], a);
        if (old == b) return;
        b = old;
    }
}

// ========== fused vote + morph + band CCL ==========
// 16 img x 32 bands = 512 blocks x 256 thr. Band = 16 owned rows (+4 halo).
// Also zeroes the global hash (512*256 threads == GHASH, one key+val each).
__global__ __launch_bounds__(256) void vmc_kernel(const float* __restrict__ x,
                                                  u64* __restrict__ mp,
                                                  u32* __restrict__ L,
                                                  u32* __restrict__ hkeys,
                                                  u32* __restrict__ hvals) {
    __shared__ u64 M[BWORDS];          // 1.5 KB
    __shared__ u32 Ll[NODES];          // 32 KB
    int blk = blockIdx.x;
    int img = blk >> 5;
    int r0  = (blk & 31) * BAND;
    int t = threadIdx.x, lane = t & 63, wv = t >> 6;

    // zero global hash
    { int idx = blk * 256 + t; hkeys[idx] = 0u; hvals[idx] = 0u; }

    // ---- vote + load (wave64 ballot -> one word) ----
    const float* xb = x + (size_t)img * 4 * IMG;
    for (int w = wv; w < BWORDS; w += 4) {
        int rr = r0 - HALO + (w >> 3);
        u64 bits = 0;
        if (rr >= 0 && rr < Hh) {                  // wave-uniform
            size_t p = (size_t)rr * Ww + (size_t)(w & 7) * 64 + lane;
            bool p1 = xb[p + (size_t)IMG]     > 0.5f;
            bool p2 = xb[p + 2 * (size_t)IMG] > 0.5f;
            bool p3 = xb[p + 3 * (size_t)IMG] > 0.5f;
            bits = __ballot(p1 | (p2 & p3));
        }
        if (lane == 0) M[w] = bits;
    }
    __syncthreads();

    // ---- 4 morph passes (close: D,E; open: E,D) ----
    #pragma unroll
    for (int pass = 0; pass < 4; ++pass) {
        const bool er = (pass == 1 || pass == 2);
        u64 res = 0;
        if (t < BWORDS) res = morph_word(M, t, r0 - HALO + (t >> 3), er);
        __syncthreads();
        if (t < BWORDS) M[t] = res;
        __syncthreads();
    }
    // owned band words: M[32 .. 159] (row r -> M[32 + r*8 + w])
    if (t < BAND * WROW)
        mp[(size_t)img * WPI + (size_t)r0 * WROW + t] = M[HALO * WROW + t];

    // ---- band CCL: nodes = within-word run starts ----
    for (int i = t; i < NODES; i += 256) Ll[i] = (u32)i;
    __syncthreads();

    // unions: 120 vertical tasks (15 row-pairs x 8 words) + 112 horizontal
    if (t < 120) {
        int rp = t >> 3, w = t & 7;                  // rows (rp, rp+1)
        u64 a = M[32 + rp * 8 + w], b = M[32 + (rp + 1) * 8 + w];
        u64 ov = a & b, seg = ov & ~(ov << 1);
        while (seg) {
            int s = __ffsll(seg) - 1; seg &= seg - 1;
            uf_merge((u32*)Ll, (u32)(rp * Ww + w * 64) + runstart(a, s),
                               (u32)((rp + 1) * Ww + w * 64) + runstart(b, s));
        }
    } else if (t < 232) {
        int ht = t - 120, r = ht / 7, w = 1 + ht % 7;  // word pair (w-1, w)
        u64 a = M[32 + r * 8 + w - 1], b = M[32 + r * 8 + w];
        if ((a >> 63) & b & 1ULL)
            uf_merge((u32*)Ll, (u32)(r * Ww + (w - 1) * 64) + runstart(a, 63),
                               (u32)(r * Ww + w * 64));
    }
    __syncthreads();

    // flatten per run + write global L (128 word tasks)
    u32 pbase = (u32)img * IMG + (u32)r0 * Ww;    // node n -> pixel pbase+n
    if (t < 128) {
        u64 bits = M[32 + t];
        u32 nb = (u32)(t >> 3) * Ww + (u32)(t & 7) * 64;
        u64 st = bits & ~(bits << 1);
        while (st) {
            int s = __ffsll(st) - 1; st &= st - 1;
            u32 n = nb + (u32)s;
            u32 r = n, p = Ll[r];
            while (p != r) { r = p; p = Ll[r]; }   // read-only chase
            L[pbase + n] = pbase + r;
        }
    }
}

// ========== cross-band boundary merges ==========
#define BITEMS (BATCH * 31 * WROW)    // 3968
__global__ void border_merge_kernel(const u64* __restrict__ mp, u32* L) {
    int e = blockIdx.x * blockDim.x + threadIdx.x;
    if (e >= BITEMS) return;
    int w = e & 7, k = (e >> 3) % 31 + 1, img = e / (31 * 8);
    int R = k * BAND;                  // boundary rows R-1, R
    const u64* ib = mp + (size_t)img * WPI;
    u64 a = ib[(size_t)(R - 1) * WROW + w];
    u64 b = ib[(size_t)R * WROW + w];
    u64 ov = a & b, seg = ov & ~(ov << 1);
    u32 ga = (u32)img * IMG + (u32)(R - 1) * Ww + (u32)(w * 64);
    while (seg) {
        int s = __ffsll(seg) - 1; seg &= seg - 1;
        uf_merge(L, ga + runstart(a, s), ga + (u32)Ww + runstart(b, s));
    }
}

// ========== count: per-word runs -> LDS hash -> global hash ==========
__global__ __launch_bounds__(256) void count_kernel(const u64* __restrict__ mp,
                                                    u32* __restrict__ L,
                                                    u32* __restrict__ hkeys,
                                                    u32* __restrict__ hvals) {
    __shared__ u32 keys[LHASH];
    __shared__ u32 vals[LHASH];
    int tid = threadIdx.x;
    for (int i = tid; i < LHASH; i += 256) { keys[i] = 0xFFFFFFFFu; vals[i] = 0u; }
    __syncthreads();

    int widx = blockIdx.x * 256 + tid;        // exact grid: NWORDS threads
    u64 bits = mp[widx];
    u32 gbase = (u32)widx * 64;
    u64 st = bits & ~(bits << 1);
    while (st) {
        int s = __ffsll(st) - 1; st &= st - 1;
        u32 node = gbase + (u32)s;
        u32 r = node, p = L[r];
        while (p != r) { r = p; p = L[r]; }   // short: node->band root->chain
        L[node] = r;                           // own-slot compress for final
        u32 len = runlen(bits, s);
        u32 h = (r * 2654435761u) & (LHASH - 1);
        while (true) {
            u32 k = atomicCAS(&keys[h], 0xFFFFFFFFu, r);
            if (k == 0xFFFFFFFFu || k == r) { atomicAdd(&vals[h], len); break; }
            h = (h + 1) & (LHASH - 1);
        }
    }
    __syncthreads();
    for (int i = tid; i < LHASH; i += 256) {
        u32 k = keys[i];
        if (k != 0xFFFFFFFFu) {
            u32 h = (k * 2654435761u) & (GHASH - 1);
            while (true) {
                u32 kk = atomicCAS(&hkeys[h], 0u, k + 1u);
                if (kk == 0u || kk == k + 1u) { atomicAdd(&hvals[h], vals[i]); break; }
                h = (h + 1) & (GHASH - 1);
            }
        }
    }
}

// ========== final: keep-mask per word, coalesced float4 writes ==========
__global__ __launch_bounds__(256) void final_kernel(const u64* __restrict__ mp,
                                                    const u32* __restrict__ L,
                                                    const u32* __restrict__ hkeys,
                                                    const u32* __restrict__ hvals,
                                                    float* __restrict__ out) {
    __shared__ u64 km[256];
    int tid = threadIdx.x;
    int widx = blockIdx.x * 256 + tid;
    u64 bits = mp[widx];
    u32 gbase = (u32)widx * 64;
    u64 keep = 0;
    u64 st = bits & ~(bits << 1);
    while (st) {
        int s = __ffsll(st) - 1; st &= st - 1;
        u32 r = L[gbase + (u32)s];           // exact root (count compressed)
        u32 h = (r * 2654435761u) & (GHASH - 1);
        u32 szv = 0;
        while (true) {
            u32 k = hkeys[h];
            if (k == r + 1u) { szv = hvals[h]; break; }
            if (k == 0u) break;
            h = (h + 1) & (GHASH - 1);
        }
        if (szv > MIN_SIZE) {
            u32 len = runlen(bits, s);
            keep |= (len == 64 ? ~0ULL : ((1ULL << len) - 1ULL)) << s;
        }
    }
    km[tid] = keep;
    __syncthreads();
    float4* o4 = (float4*)out + (size_t)blockIdx.x * 4096;
    for (int i = tid; i < 4096; i += 256) {
        u32 nib = (u32)(km[i >> 4] >> ((i & 15) * 4)) & 0xFu;
        o4[i] = make_float4(nib & 1u ? 1.f : 0.f, nib & 2u ? 1.f : 0.f,
                            nib & 4u ? 1.f : 0.f, nib & 8u ? 1.f : 0.f);
    }
}

extern "C" void kernel_launch(void* const* d_in, const int* in_sizes, int n_in,
                              void* d_out, int out_size, void* d_ws, size_t ws_size,
                              hipStream_t stream) {
    const float* x = (const float*)d_in[0];
    float* out = (float*)d_out;

    // ws: mp 512KB | L 16MB | hkeys 512KB | hvals 512KB  (~17.5MB)
    u64* mp = (u64*)d_ws;
    u32* L  = (u32*)(mp + NWORDS);
    u32* hkeys = L + TOT;
    u32* hvals = hkeys + GHASH;

    const int block = 256;

    vmc_kernel<<<BATCH * 32, block, 0, stream>>>(x, mp, L, hkeys, hvals);
    border_merge_kernel<<<(BITEMS + block - 1) / block, block, 0, stream>>>(mp, L);
    count_kernel<<<NWORDS / block, block, 0, stream>>>(mp, L, hkeys, hvals);
    final_kernel<<<NWORDS / block, block, 0, stream>>>(mp, L, hkeys, hvals, out);
}

// Round 10
// 104.239 us; speedup vs baseline: 1.4284x; 1.0451x over previous
//
#include <hip/hip_runtime.h>

typedef unsigned long long u64;
typedef unsigned u32;

#define BATCH 16
#define Hh 512
#define Ww 512
#define IMG (Hh * Ww)          // 262144
#define TOT (BATCH * IMG)      // 4194304
#define WPI (IMG / 64)         // 4096 words per image
#define WROW 8                 // words per row
#define NWORDS (TOT / 64)      // 65536
#define MIN_SIZE 262           // keep strictly greater
#define GHASH 131072           // global root->size hash (power of 2, load ~0.3)
#define LHASH 2048             // per-block hash in count

#define BAND 8
#define HALO 4
#define BROWS (BAND + 2 * HALO)     // 16
#define BWORDS (BROWS * WROW)       // 128
#define NODES (BAND * Ww)           // 4096 nodes per band

// run start within a 64-bit word: nearest zero at-or-below bit s, +1.
__device__ __forceinline__ u32 runstart(u64 bits, int s) {
    u64 ms = (s >= 63) ? ~0ULL : ((1ULL << (s + 1)) - 1);
    u64 nz = ~bits & ms;
    return nz ? (u32)(64 - __clzll(nz)) : 0u;
}
// run length starting at set bit s (within word)
__device__ __forceinline__ u32 runlen(u64 bits, int s) {
    u64 v = ~(bits >> s);
    return v ? (u32)(__ffsll(v) - 1) : (u32)(64 - s);
}

__device__ __forceinline__ u64 morph_word(const u64* M, int w, int rr, bool er) {
    const u64 B = er ? ~0ULL : 0ULL;
    int wx = w & 7;
    u64 cc = M[w];
    u64 lf = (cc << 1) | (wx > 0 ? (M[w - 1] >> 63) : (er ? 1ULL : 0ULL));
    u64 rt = (cc >> 1) | (wx < 7 ? (M[w + 1] << 63) : (er ? (1ULL << 63) : 0ULL));
    u64 up = (rr <= 0)      ? B : (w >= WROW          ? M[w - WROW] : B);
    u64 dn = (rr >= Hh - 1) ? B : (w < BWORDS - WROW  ? M[w + WROW] : B);
    return er ? (cc & lf & rt & up & dn) : (cc | lf | rt | up | dn);
}

// ---------------- union-find primitives (LDS or global) ----------------
template <typename P>
__device__ __forceinline__ u32 uf_find_halve(P L, u32 x) {
    while (true) {
        u32 p = L[x];
        if (p == x) return x;
        u32 gp = L[p];
        if (gp == p) return p;
        atomicMin(&L[x], gp);   // halving: gp <= p < x, monotone-safe
        x = gp;
    }
}
template <typename P>
__device__ __forceinline__ void uf_merge(P L, u32 a, u32 b) {
    while (true) {
        a = uf_find_halve(L, a);
        b = uf_find_halve(L, b);
        if (a == b) return;
        if (a > b) { u32 t = a; a = b; b = t; }   // a < b
        u32 old = atomicMin(&L[b], a);
        if (old == b) return;
        b = old;
    }
}

// ========== vote + bitpack (pure streaming, full occupancy) ==========
// 2048 blocks x 256 thr; each wave produces 8 words via grid-stride.
// Also zeroes the global hash (2048*256 = 524288 >= 2*GHASH).
__global__ __launch_bounds__(256) void vote_pack_kernel(const float* __restrict__ x,
                                                        u64* __restrict__ mp0,
                                                        u32* __restrict__ hkeys,
                                                        u32* __restrict__ hvals) {
    int t = threadIdx.x, lane = t & 63;
    { int idx = blockIdx.x * 256 + t;
      if (idx < GHASH) hkeys[idx] = 0u;
      else if (idx < 2 * GHASH) hvals[idx - GHASH] = 0u; }

    int wave = blockIdx.x * 4 + (t >> 6);            // 8192 waves
    for (int k = 0; k < 8; ++k) {
        int word = wave + k * 8192;                  // < NWORDS
        int img = word >> 12;
        size_t p = (size_t)(word & 4095) * 64 + lane;
        const float* xb = x + (size_t)img * 4 * IMG;
        bool p1 = xb[p + (size_t)IMG]     > 0.5f;
        bool p2 = xb[p + 2 * (size_t)IMG] > 0.5f;
        bool p3 = xb[p + 3 * (size_t)IMG] > 0.5f;
        u64 bits = __ballot(p1 | (p2 & p3));
        if (lane == 0) mp0[word] = bits;
    }
}

// ========== morph (4 passes) + band CCL, packed input ==========
// 16 img x 64 bands of 8 rows = 1024 blocks x 256 thr. Input: packed vote
// mask (512 KB, L2-resident). LDS: M 1KB + Ll 16KB.
__global__ __launch_bounds__(256) void morph_ccl_kernel(const u64* __restrict__ mp0,
                                                        u64* __restrict__ mp,
                                                        u32* __restrict__ L) {
    __shared__ u64 M[BWORDS];
    __shared__ u32 Ll[NODES];
    int blk = blockIdx.x;
    int img = blk >> 6;
    int r0  = (blk & 63) * BAND;
    int t = threadIdx.x;

    if (t < BWORDS) {
        int rr = r0 - HALO + (t >> 3);
        M[t] = (rr >= 0 && rr < Hh) ? mp0[(size_t)img * WPI + (size_t)rr * WROW + (t & 7)] : 0;
    }
    __syncthreads();

    #pragma unroll
    for (int pass = 0; pass < 4; ++pass) {
        const bool er = (pass == 1 || pass == 2);    // close: D,E  open: E,D
        u64 res = 0;
        if (t < BWORDS) res = morph_word(M, t, r0 - HALO + (t >> 3), er);
        __syncthreads();
        if (t < BWORDS) M[t] = res;
        __syncthreads();
    }
    // owned rows: M[HALO*8 .. HALO*8+63]
    if (t < BAND * WROW)
        mp[(size_t)img * WPI + (size_t)r0 * WROW + t] = M[HALO * WROW + t];

    // ---- band CCL: nodes = within-word run starts ----
    for (int i = t; i < NODES; i += 256) Ll[i] = (u32)i;
    __syncthreads();

    // unions: 56 vertical (7 row-pairs x 8 words) + 56 horizontal (8 rows x 7)
    if (t < 56) {
        int rp = t >> 3, w = t & 7;                  // rows (rp, rp+1)
        u64 a = M[HALO * WROW + rp * 8 + w], b = M[HALO * WROW + (rp + 1) * 8 + w];
        u64 ov = a & b, seg = ov & ~(ov << 1);
        while (seg) {
            int s = __ffsll(seg) - 1; seg &= seg - 1;
            uf_merge((u32*)Ll, (u32)(rp * Ww + w * 64) + runstart(a, s),
                               (u32)((rp + 1) * Ww + w * 64) + runstart(b, s));
        }
    } else if (t >= 64 && t < 120) {
        int ht = t - 64, r = ht >> 3, w = 1 + (ht & 7) % 7;  // rows 0..7, words 1..7
        // remap: ht = r*8 + c with c 0..7 -> need c 0..6; use r = ht/7 instead
        r = ht / 7; w = 1 + ht % 7;
        u64 a = M[HALO * WROW + r * 8 + w - 1], b = M[HALO * WROW + r * 8 + w];
        if ((a >> 63) & b & 1ULL)
            uf_merge((u32*)Ll, (u32)(r * Ww + (w - 1) * 64) + runstart(a, 63),
                               (u32)(r * Ww + w * 64));
    }
    __syncthreads();

    // flatten per run + write global L (64 word tasks)
    u32 pbase = (u32)img * IMG + (u32)r0 * Ww;    // node n -> pixel pbase+n
    if (t < 64) {
        u64 bits = M[HALO * WROW + t];
        u32 nb = (u32)(t >> 3) * Ww + (u32)(t & 7) * 64;
        u64 st = bits & ~(bits << 1);
        while (st) {
            int s = __ffsll(st) - 1; st &= st - 1;
            u32 n = nb + (u32)s;
            u32 r = n, p = Ll[r];
            while (p != r) { r = p; p = Ll[r]; }   // read-only chase
            L[pbase + n] = pbase + r;
        }
    }
}

// ========== cross-band boundary merges ==========
#define BITEMS (BATCH * 63 * WROW)    // 8064
__global__ void border_merge_kernel(const u64* __restrict__ mp, u32* L) {
    int e = blockIdx.x * blockDim.x + threadIdx.x;
    if (e >= BITEMS) return;
    int w = e & 7, k = (e >> 3) % 63 + 1, img = e / (63 * 8);
    int R = k * BAND;                  // boundary rows R-1, R
    const u64* ib = mp + (size_t)img * WPI;
    u64 a = ib[(size_t)(R - 1) * WROW + w];
    u64 b = ib[(size_t)R * WROW + w];
    u64 ov = a & b, seg = ov & ~(ov << 1);
    u32 ga = (u32)img * IMG + (u32)(R - 1) * Ww + (u32)(w * 64);
    while (seg) {
        int s = __ffsll(seg) - 1; seg &= seg - 1;
        uf_merge(L, ga + runstart(a, s), ga + (u32)Ww + runstart(b, s));
    }
}

// ========== count: per-word runs -> LDS hash -> global hash ==========
__global__ __launch_bounds__(256) void count_kernel(const u64* __restrict__ mp,
                                                    u32* __restrict__ L,
                                                    u32* __restrict__ hkeys,
                                                    u32* __restrict__ hvals) {
    __shared__ u32 keys[LHASH];
    __shared__ u32 vals[LHASH];
    int tid = threadIdx.x;
    for (int i = tid; i < LHASH; i += 256) { keys[i] = 0xFFFFFFFFu; vals[i] = 0u; }
    __syncthreads();

    int widx = blockIdx.x * 256 + tid;        // exact grid: NWORDS threads
    u64 bits = mp[widx];
    u32 gbase = (u32)widx * 64;
    u64 st = bits & ~(bits << 1);
    while (st) {
        int s = __ffsll(st) - 1; st &= st - 1;
        u32 node = gbase + (u32)s;
        u32 r = node, p = L[r];
        while (p != r) { r = p; p = L[r]; }   // short: node->band root->chain
        L[node] = r;                           // own-slot compress for final
        u32 len = runlen(bits, s);
        u32 h = (r * 2654435761u) & (LHASH - 1);
        while (true) {
            u32 k = atomicCAS(&keys[h], 0xFFFFFFFFu, r);
            if (k == 0xFFFFFFFFu || k == r) { atomicAdd(&vals[h], len); break; }
            h = (h + 1) & (LHASH - 1);
        }
    }
    __syncthreads();
    for (int i = tid; i < LHASH; i += 256) {
        u32 k = keys[i];
        if (k != 0xFFFFFFFFu) {
            u32 h = (k * 2654435761u) & (GHASH - 1);
            while (true) {
                u32 kk = atomicCAS(&hkeys[h], 0u, k + 1u);
                if (kk == 0u || kk == k + 1u) { atomicAdd(&hvals[h], vals[i]); break; }
                h = (h + 1) & (GHASH - 1);
            }
        }
    }
}

// ========== final: keep-mask per word, coalesced float4 writes ==========
__global__ __launch_bounds__(256) void final_kernel(const u64* __restrict__ mp,
                                                    const u32* __restrict__ L,
                                                    const u32* __restrict__ hkeys,
                                                    const u32* __restrict__ hvals,
                                                    float* __restrict__ out) {
    __shared__ u64 km[256];
    int tid = threadIdx.x;
    int widx = blockIdx.x * 256 + tid;
    u64 bits = mp[widx];
    u32 gbase = (u32)widx * 64;
    u64 keep = 0;
    u64 st = bits & ~(bits << 1);
    while (st) {
        int s = __ffsll(st) - 1; st &= st - 1;
        u32 r = L[gbase + (u32)s];           // exact root (count compressed)
        u32 h = (r * 2654435761u) & (GHASH - 1);
        u32 szv = 0;
        while (true) {
            u32 k = hkeys[h];
            if (k == r + 1u) { szv = hvals[h]; break; }
            if (k == 0u) break;
            h = (h + 1) & (GHASH - 1);
        }
        if (szv > MIN_SIZE) {
            u32 len = runlen(bits, s);
            keep |= (len == 64 ? ~0ULL : ((1ULL << len) - 1ULL)) << s;
        }
    }
    km[tid] = keep;
    __syncthreads();
    float4* o4 = (float4*)out + (size_t)blockIdx.x * 4096;
    for (int i = tid; i < 4096; i += 256) {
        u32 nib = (u32)(km[i >> 4] >> ((i & 15) * 4)) & 0xFu;
        o4[i] = make_float4(nib & 1u ? 1.f : 0.f, nib & 2u ? 1.f : 0.f,
                            nib & 4u ? 1.f : 0.f, nib & 8u ? 1.f : 0.f);
    }
}

extern "C" void kernel_launch(void* const* d_in, const int* in_sizes, int n_in,
                              void* d_out, int out_size, void* d_ws, size_t ws_size,
                              hipStream_t stream) {
    const float* x = (const float*)d_in[0];
    float* out = (float*)d_out;

    // ws: mp0 512KB | mp 512KB | L 16MB | hkeys 512KB | hvals 512KB  (~18MB)
    u64* mp0 = (u64*)d_ws;
    u64* mp  = mp0 + NWORDS;
    u32* L   = (u32*)(mp + NWORDS);
    u32* hkeys = L + TOT;
    u32* hvals = hkeys + GHASH;

    const int block = 256;

    vote_pack_kernel<<<2048, block, 0, stream>>>(x, mp0, hkeys, hvals);
    morph_ccl_kernel<<<BATCH * 64, block, 0, stream>>>(mp0, mp, L);
    border_merge_kernel<<<(BITEMS + block - 1) / block, block, 0, stream>>>(mp, L);
    count_kernel<<<NWORDS / block, block, 0, stream>>>(mp, L, hkeys, hvals);
    final_kernel<<<NWORDS / block, block, 0, stream>>>(mp, L, hkeys, hvals, out);
}